// Round 8
// baseline (141.025 us; speedup 1.0000x reference)
//
#include <hip/hip_runtime.h>
#include <math.h>

// B=16384 rows, C=1000 cols, fp32 -> 16384 fp32.
//
// R11 = R10 (nt loads, netsat < 40.6 us — absent from top-5 for the first
// time; R9 baseline was 44.3-44.8) with ONE variable changed: loads are now
// full-bypass streaming reads (sc0 sc1 nt) via inline asm.
//
// Evidence trail: R10's nt bit alone bought >=8%, falsifying the "physical
// 3.15 TB/s read path" model — part of the cap was cache-ALLOCATE policy.
// This kernel has zero read reuse (each row read once by one block), so
// L1/L2 line fills are pure overhead; sc0 sc1 nt streams reads past them.
// One load round-trip per block, 8+ resident blocks/CU to overlap it.
//
// PRE-COMMITTED READ: <37 us => continue on policy axis. 40-46 us =>
// declare ROOFLINE (~3.3 TB/s streaming-read ceiling). >46 us => sc bits
// hit the slow coherent path; revert to R10 and declare.

constexpr int kC  = 1000;
constexpr int kNV = kC / 4;        // 250 float4 per row; threads 250..255 pad

typedef float f32x4 __attribute__((ext_vector_type(4)));

__global__ __launch_bounds__(256, 8) void netsat_kernel(
    const float* __restrict__ y1, const float* __restrict__ y2,
    float* __restrict__ out, int nrows)
{
    const int tid  = threadIdx.x;
    const int lane = tid & 63;
    const int wave = tid >> 6;
    const int row  = blockIdx.x;
    if (row >= nrows) return;

    const f32x4* r1 = reinterpret_cast<const f32x4*>(y1) + (size_t)row * kNV;
    const f32x4* r2 = reinterpret_cast<const f32x4*>(y2) + (size_t)row * kNV;

    // Unconditional clamped addresses (branchless), mask pads after load.
    const int vi = (tid < kNV) ? tid : (kNV - 1);
    const f32x4* p1 = &r1[vi];
    const f32x4* p2 = &r2[vi];

    // Full-bypass streaming loads: sc0 sc1 nt (gfx950 spelling; glc/slc do
    // not assemble). Both issue back-to-back; one counted wait; sched
    // fence so consumers can't hoist past the waitcnt (rule #18).
    f32x4 a, b;
    asm volatile(
        "global_load_dwordx4 %0, %2, off sc0 sc1 nt\n\t"
        "global_load_dwordx4 %1, %3, off sc0 sc1 nt"
        : "=&v"(a), "=&v"(b)
        : "v"(p1), "v"(p2));
    asm volatile("s_waitcnt vmcnt(0)" ::: "memory");
    __builtin_amdgcn_sched_barrier(0);

    if (tid >= kNV) {
        a = (f32x4){-INFINITY, -INFINITY, -INFINITY, -INFINITY};
        b = (f32x4){-INFINITY, -INFINITY, -INFINITY, -INFINITY};
    }

    // ---- local top-2 over this thread's 4 elements, both inputs ----
    float m1 = -INFINITY, m2 = -INFINITY;   // y1 top-2
    float n1 = -INFINITY, n2 = -INFINITY;   // y2 top-2
#pragma unroll
    for (int k = 0; k < 4; ++k) {
        const float v = a[k];
        m2 = fmaxf(m2, fminf(m1, v)); m1 = fmaxf(m1, v);
        const float w = b[k];
        n2 = fmaxf(n2, fminf(n1, w)); n1 = fmaxf(n1, w);
    }

    // ---- wave butterfly merge of (top1, top2); m/n chains interleave ----
#pragma unroll
    for (int off = 32; off > 0; off >>= 1) {
        const float o1 = __shfl_xor(m1, off, 64);
        const float o2 = __shfl_xor(m2, off, 64);
        const float p1s = __shfl_xor(n1, off, 64);
        const float p2s = __shfl_xor(n2, off, 64);
        m2 = fmaxf(fminf(m1, o1), fmaxf(m2, o2));
        m1 = fmaxf(m1, o1);
        n2 = fmaxf(fminf(n1, p1s), fmaxf(n2, p2s));
        n1 = fmaxf(n1, p1s);
    }

    // ---- cross-wave merge via LDS; every thread merges all 4 wave results
    __shared__ float sm[4][4];     // [wave] = {m1, m2, n1, n2}
    __shared__ float sbest[4];
    if (lane == 0) {
        sm[wave][0] = m1; sm[wave][1] = m2;
        sm[wave][2] = n1; sm[wave][3] = n2;
    }
    __syncthreads();

    float M1 = -INFINITY, M2 = -INFINITY, N1 = -INFINITY, N2 = -INFINITY;
#pragma unroll
    for (int w = 0; w < 4; ++w) {
        const float w1 = sm[w][0], w2 = sm[w][1];
        M2 = fmaxf(fminf(M1, w1), fmaxf(M2, w2));
        M1 = fmaxf(M1, w1);
        const float u1 = sm[w][2], u2 = sm[w][3];
        N2 = fmaxf(fminf(N1, u1), fmaxf(N2, u2));
        N1 = fmaxf(N1, u1);
    }

    // ---- pass 2 over REGISTER payload: max_j min(v - loo1, w - loo2) ----
    // loo(v) = (v==M1) ? M2 : M1 — tie-safe (duplicated max => M2==M1).
    float best = -INFINITY;
#pragma unroll
    for (int k = 0; k < 4; ++k) {
        const float v = a[k];
        const float w = b[k];
        const float l1 = (v == M1) ? M2 : M1;
        const float l2 = (w == N1) ? N2 : N1;
        best = fmaxf(best, fminf(v - l1, w - l2));
    }
#pragma unroll
    for (int off = 32; off > 0; off >>= 1)
        best = fmaxf(best, __shfl_xor(best, off, 64));

    if (lane == 0) sbest[wave] = best;
    __syncthreads();

    if (tid == 0) {
        float r = fmaxf(fmaxf(sbest[0], sbest[1]), fmaxf(sbest[2], sbest[3]));
        out[row] = r;
    }
}

extern "C" void kernel_launch(void* const* d_in, const int* in_sizes, int n_in,
                              void* d_out, int out_size, void* d_ws, size_t ws_size,
                              hipStream_t stream) {
    const float* y1 = (const float*)d_in[0];
    const float* y2 = (const float*)d_in[1];
    float* out = (float*)d_out;
    const int nrows = out_size;  // 16384
    netsat_kernel<<<nrows, 256, 0, stream>>>(y1, y2, out, nrows);
}